// Round 1
// baseline (279.214 us; speedup 1.0000x reference)
//
#include <hip/hip_runtime.h>

typedef __bf16 bf16;
typedef __bf16 bf16x4 __attribute__((ext_vector_type(4)));
typedef __bf16 bf16x8 __attribute__((ext_vector_type(8)));
typedef float f32x4 __attribute__((ext_vector_type(4)));

#define LOG2E 1.44269504088896f

// ---------------- cast fp32 -> bf16 for weights + persistent mem ----------------
__global__ void cast3_kernel(const float* __restrict__ a, int na4, bf16* __restrict__ oa,
                             const float* __restrict__ b, int nb4, bf16* __restrict__ ob,
                             const float* __restrict__ c, int nc4, bf16* __restrict__ oc) {
  int i = blockIdx.x * blockDim.x + threadIdx.x;
  const float* src; bf16* dst; int idx;
  if (i < na4)            { src = a; dst = oa; idx = i; }
  else if (i < na4 + nb4) { src = b; dst = ob; idx = i - na4; }
  else if (i < na4 + nb4 + nc4) { src = c; dst = oc; idx = i - na4 - nb4; }
  else return;
  float4 v = ((const float4*)src)[idx];
  bf16x4 o = { (bf16)v.x, (bf16)v.y, (bf16)v.z, (bf16)v.w };
  ((bf16x4*)dst)[idx] = o;
}

// ---------------- RMSNorm: seq fp32 [8192][1024] -> x bf16 ----------------
__global__ __launch_bounds__(256) void rmsnorm_kernel(const float* __restrict__ seq,
                                                      const float* __restrict__ g,
                                                      bf16* __restrict__ xbf) {
  int row = blockIdx.x;
  int t = threadIdx.x;
  float4 x = ((const float4*)(seq + (size_t)row * 1024))[t];
  float ss = x.x*x.x + x.y*x.y + x.z*x.z + x.w*x.w;
  #pragma unroll
  for (int m = 32; m >= 1; m >>= 1) ss += __shfl_xor(ss, m, 64);
  __shared__ float red[4];
  if ((t & 63) == 0) red[t >> 6] = ss;
  __syncthreads();
  float tot = red[0] + red[1] + red[2] + red[3];
  float scale = rsqrtf(tot * (1.0f / 1024.0f) + 1.1920929e-07f);
  float4 gv = ((const float4*)g)[t];
  bf16x4 o = { (bf16)(x.x*scale*gv.x), (bf16)(x.y*scale*gv.y),
               (bf16)(x.z*scale*gv.z), (bf16)(x.w*scale*gv.w) };
  ((bf16x4*)(xbf + (size_t)row * 1024))[t] = o;
}

// ---------------- GEMM C[M,N] = A[M,K] * B[N,K]^T  (bf16 in, bf16/fp32 out) ----------------
// 128x128 tile, BK=32, 256 threads (4 waves, each 64x64 as 4x4 16x16 frags)
template<int OUTF>
__global__ __launch_bounds__(256) void gemm_bt_kernel(const bf16* __restrict__ A,
                                                      const bf16* __restrict__ B,
                                                      void* __restrict__ C,
                                                      int M, int N, int K) {
  __shared__ bf16 As[128 * 40];
  __shared__ bf16 Bs[128 * 40];
  int t = threadIdx.x;
  int lane = t & 63, wv = t >> 6;
  int m16 = lane & 15, quad = lane >> 4;
  int bn = blockIdx.x, bm = blockIdx.y;
  const bf16* Ab = A + (size_t)bm * 128 * K;
  const bf16* Bb = B + (size_t)bn * 128 * K;
  int wr = (wv >> 1) * 64, wc = (wv & 1) * 64;
  f32x4 acc[4][4] = {};
  for (int k0 = 0; k0 < K; k0 += 32) {
    #pragma unroll
    for (int i = 0; i < 2; i++) {
      int ch = t + i * 256;            // 512 chunks of 16B per matrix
      int row = ch >> 2, c = (ch & 3) * 8;
      *(uint4*)(&As[row * 40 + c]) = *(const uint4*)(Ab + (size_t)row * K + k0 + c);
      *(uint4*)(&Bs[row * 40 + c]) = *(const uint4*)(Bb + (size_t)row * K + k0 + c);
    }
    __syncthreads();
    bf16x8 af[4], bfr[4];
    #pragma unroll
    for (int i = 0; i < 4; i++) af[i]  = *(const bf16x8*)(&As[(wr + i * 16 + m16) * 40 + quad * 8]);
    #pragma unroll
    for (int j = 0; j < 4; j++) bfr[j] = *(const bf16x8*)(&Bs[(wc + j * 16 + m16) * 40 + quad * 8]);
    #pragma unroll
    for (int i = 0; i < 4; i++)
      #pragma unroll
      for (int j = 0; j < 4; j++)
        acc[i][j] = __builtin_amdgcn_mfma_f32_16x16x32_bf16(af[i], bfr[j], acc[i][j], 0, 0, 0);
    __syncthreads();
  }
  #pragma unroll
  for (int i = 0; i < 4; i++)
    #pragma unroll
    for (int j = 0; j < 4; j++)
      #pragma unroll
      for (int r = 0; r < 4; r++) {
        size_t row = (size_t)bm * 128 + wr + i * 16 + quad * 4 + r;
        size_t col = (size_t)bn * 128 + wc + j * 16 + m16;
        float v = acc[i][j][r];
        if (OUTF) ((float*)C)[row * N + col] = v;
        else      ((bf16*)C)[row * N + col] = (bf16)v;
      }
}

// ---------------- RoPE + segment rearrange ----------------
// qkv bf16 [8192][3072] -> q [16][16][512][64] (pre-scaled by 1/8), k/v [16][16][528][64] rows 16..527
__global__ __launch_bounds__(128) void rope_seg_kernel(const bf16* __restrict__ qkv,
                                                       bf16* __restrict__ qa,
                                                       bf16* __restrict__ ka,
                                                       bf16* __restrict__ va) {
  int row = blockIdx.x, t = threadIdx.x;       // 8192 rows, 128 threads
  int h = t >> 3, d0 = (t & 7) * 8;
  int gb = row >> 12, pos = row & 4095, seg = (row >> 9) & 7, s = row & 511;
  const bf16* base = qkv + (size_t)row * 3072 + h * 64 + d0;
  bf16 qv[8], kv[8], vv[8];
  *(uint4*)qv = *(const uint4*)(base);
  *(uint4*)kv = *(const uint4*)(base + 1024);
  *(uint4*)vv = *(const uint4*)(base + 2048);
  bf16 qo[8], ko[8];
  #pragma unroll
  for (int p = 0; p < 4; p++) {
    int fi = (d0 >> 1) + p;                    // freq index 0..31
    float inv = exp2f((float)fi * -0.41524101186f);   // 10000^(-fi/32)
    float th = (float)pos * inv;
    float sn, cs;
    sincosf(th, &sn, &cs);
    float q0 = (float)qv[2 * p], q1 = (float)qv[2 * p + 1];
    float k0 = (float)kv[2 * p], k1 = (float)kv[2 * p + 1];
    qo[2 * p]     = (bf16)((q0 * cs - q1 * sn) * 0.125f);
    qo[2 * p + 1] = (bf16)((q1 * cs + q0 * sn) * 0.125f);
    ko[2 * p]     = (bf16)(k0 * cs - k1 * sn);
    ko[2 * p + 1] = (bf16)(k1 * cs + k0 * sn);
  }
  size_t bwh = ((size_t)(gb * 8 + seg) * 16 + h);
  size_t qoff = (bwh * 512 + s) * 64 + d0;
  *(uint4*)(qa + qoff) = *(uint4*)qo;
  size_t koff = (bwh * 528 + 16 + s) * 64 + d0;
  *(uint4*)(ka + koff) = *(uint4*)ko;
  *(uint4*)(va + koff) = *(uint4*)vv;
}

// ---------------- persistent-mem fill: k/v rows 0..15 ----------------
__global__ void pm_fill_kernel(const bf16* __restrict__ pmbf,
                               bf16* __restrict__ ka, bf16* __restrict__ va) {
  int idx = blockIdx.x * blockDim.x + threadIdx.x;   // 2*16*16*16*64 = 524288
  int d = idx & 63, r = (idx >> 6) & 15, h = (idx >> 10) & 15, bw = (idx >> 14) & 15, which = idx >> 18;
  bf16 val = pmbf[(((size_t)which * 16 + h) * 16 + r) * 64 + d];
  size_t off = (((size_t)bw * 16 + h) * 528 + r) * 64 + d;
  bf16* dst = which ? va : ka;
  dst[off] = val;
}

// ---------------- attention: one block per (bw,h), 8 waves ----------------
__global__ __launch_bounds__(512) void attn_kernel(const bf16* __restrict__ qa,
                                                   const bf16* __restrict__ ka,
                                                   const bf16* __restrict__ va,
                                                   bf16* __restrict__ ob) {
  __shared__ bf16 Ks[528 * 72];          // K rows, padded stride 72 (2-way bank alias = free)
  __shared__ bf16 Vt[64 * 536 + 16];     // V transposed [d][j], stride 536, zero-padded tail
  __shared__ bf16 Pb[8 * 16 * 40];       // per-wave P staging, stride 40
  int bh = blockIdx.x;
  int bw = bh >> 4, h = bh & 15;
  int t = threadIdx.x;
  int wv = t >> 6, lane = t & 63;
  int m16 = lane & 15, quad = lane >> 4;
  const bf16* kbase = ka + (size_t)bh * 528 * 64;
  const bf16* vbase = va + (size_t)bh * 528 * 64;
  const bf16* qbase = qa + (size_t)bh * 512 * 64;
  // stage K rows
  for (int ch = t; ch < 4224; ch += 512) {
    int row = ch >> 3, c8 = (ch & 7) * 8;
    *(uint4*)(&Ks[row * 72 + c8]) = *(const uint4*)(kbase + row * 64 + c8);
  }
  // stage V transposed
  for (int ch = t; ch < 4224; ch += 512) {
    int row = ch >> 3, d0 = (ch & 7) * 8;
    uint4 dta = *(const uint4*)(vbase + row * 64 + d0);
    bf16 tmp[8]; *(uint4*)tmp = dta;
    #pragma unroll
    for (int i = 0; i < 8; i++) Vt[(d0 + i) * 536 + row] = tmp[i];
  }
  // zero-pad Vt cols 528..535 and the tail so the ragged last chunk reads finite zeros
  if (t < 512) { int r = t >> 3, cc = 528 + (t & 7); Vt[r * 536 + cc] = (bf16)0.f; }
  if (t < 16) Vt[64 * 536 + t] = (bf16)0.f;
  __syncthreads();

  bf16* myP = &Pb[wv * 16 * 40];
  for (int pass = 0; pass < 4; pass++) {
    int q0 = pass * 128 + wv * 16;
    bf16x8 qf0 = *(const bf16x8*)(qbase + (size_t)(q0 + m16) * 64 + quad * 8);
    bf16x8 qf1 = *(const bf16x8*)(qbase + (size_t)(q0 + m16) * 64 + 32 + quad * 8);
    f32x4 s[33];
    #pragma unroll
    for (int tl = 0; tl < 33; tl++) {
      f32x4 acc = {0.f, 0.f, 0.f, 0.f};
      bf16x8 b0 = *(const bf16x8*)(&Ks[(tl * 16 + m16) * 72 + quad * 8]);
      bf16x8 b1 = *(const bf16x8*)(&Ks[(tl * 16 + m16) * 72 + 32 + quad * 8]);
      acc = __builtin_amdgcn_mfma_f32_16x16x32_bf16(qf0, b0, acc, 0, 0, 0);
      acc = __builtin_amdgcn_mfma_f32_16x16x32_bf16(qf1, b1, acc, 0, 0, 0);
      s[tl] = acc;
    }
    // causal mask: query i sees kv j iff j-16 <= i
    #pragma unroll
    for (int tl = 0; tl < 33; tl++) {
      int j = tl * 16 + m16;
      #pragma unroll
      for (int r = 0; r < 4; r++) {
        int i = q0 + quad * 4 + r;
        if (j - 16 > i) s[tl][r] = -1e30f;
      }
    }
    // softmax (full row available): reduce over 33 tiles + 16 lanes of the column group
    float lrow[4];
    #pragma unroll
    for (int r = 0; r < 4; r++) {
      float mx = s[0][r];
      #pragma unroll
      for (int tl = 1; tl < 33; tl++) mx = fmaxf(mx, s[tl][r]);
      mx = fmaxf(mx, __shfl_xor(mx, 1, 64));
      mx = fmaxf(mx, __shfl_xor(mx, 2, 64));
      mx = fmaxf(mx, __shfl_xor(mx, 4, 64));
      mx = fmaxf(mx, __shfl_xor(mx, 8, 64));
      float sum = 0.f;
      #pragma unroll
      for (int tl = 0; tl < 33; tl++) {
        float p = exp2f((s[tl][r] - mx) * LOG2E);
        s[tl][r] = p;
        sum += p;
      }
      sum += __shfl_xor(sum, 1, 64);
      sum += __shfl_xor(sum, 2, 64);
      sum += __shfl_xor(sum, 4, 64);
      sum += __shfl_xor(sum, 8, 64);
      lrow[r] = sum;
    }
    // PV: 17 chunks of 32 kv (last half-chunk zero-padded)
    f32x4 o[4] = {};
    for (int c = 0; c < 17; c++) {
      #pragma unroll
      for (int half = 0; half < 2; half++) {
        int tl = 2 * c + half;
        #pragma unroll
        for (int r = 0; r < 4; r++) {
          float pv = (tl < 33) ? s[tl][r] : 0.f;
          myP[(quad * 4 + r) * 40 + half * 16 + m16] = (bf16)pv;
        }
      }
      asm volatile("s_waitcnt lgkmcnt(0)" ::: "memory");   // wave-local: writes visible
      bf16x8 pf = *(const bf16x8*)(&myP[m16 * 40 + quad * 8]);
      #pragma unroll
      for (int dt = 0; dt < 4; dt++) {
        bf16x8 vf = *(const bf16x8*)(&Vt[(dt * 16 + m16) * 536 + c * 32 + quad * 8]);
        o[dt] = __builtin_amdgcn_mfma_f32_16x16x32_bf16(pf, vf, o[dt], 0, 0, 0);
      }
      asm volatile("s_waitcnt lgkmcnt(0)" ::: "memory");   // reads done before next overwrite
    }
    // normalize + write to [8192][1024] merged layout
    int gb = bw >> 3, seg = bw & 7;
    float invl[4];
    #pragma unroll
    for (int r = 0; r < 4; r++) invl[r] = 1.0f / lrow[r];
    #pragma unroll
    for (int dt = 0; dt < 4; dt++)
      #pragma unroll
      for (int r = 0; r < 4; r++) {
        size_t row = (size_t)gb * 4096 + seg * 512 + q0 + quad * 4 + r;
        ob[row * 1024 + h * 64 + dt * 16 + m16] = (bf16)(o[dt][r] * invl[r]);
      }
  }
}

// ---------------- launch ----------------
extern "C" void kernel_launch(void* const* d_in, const int* in_sizes, int n_in,
                              void* d_out, int out_size, void* d_ws, size_t ws_size,
                              hipStream_t stream) {
  const float* seq  = (const float*)d_in[0];
  const float* g    = (const float*)d_in[1];
  const float* wqkv = (const float*)d_in[2];
  const float* wout = (const float*)d_in[3];
  const float* pm   = (const float*)d_in[4];
  float* out = (float*)d_out;
  char* ws = (char*)d_ws;
  bf16* wqkv_bf = (bf16*)(ws);                    //  6,291,456
  bf16* wout_bf = (bf16*)(ws + 6291456);          //  2,097,152
  bf16* pm_bf   = (bf16*)(ws + 8388608);          //     65,536 (32768 elems)
  bf16* x_bf    = (bf16*)(ws + 8454144);          // 16,777,216 (reused as attn out)
  bf16* qkv_bf  = (bf16*)(ws + 25231360);         // 50,331,648
  bf16* q_arr   = (bf16*)(ws + 75563008);         // 16,777,216
  bf16* k_arr   = (bf16*)(ws + 92340224);         // 17,301,504
  bf16* v_arr   = (bf16*)(ws + 109641728);        // 17,301,504 -> 126,943,232 total

  cast3_kernel<<<4128, 256, 0, stream>>>(wqkv, 786432, wqkv_bf,
                                         wout, 262144, wout_bf,
                                         pm, 8192, pm_bf);
  rmsnorm_kernel<<<8192, 256, 0, stream>>>(seq, g, x_bf);
  gemm_bt_kernel<0><<<dim3(24, 64), 256, 0, stream>>>(x_bf, wqkv_bf, qkv_bf, 8192, 3072, 1024);
  rope_seg_kernel<<<8192, 128, 0, stream>>>(qkv_bf, q_arr, k_arr, v_arr);
  pm_fill_kernel<<<2048, 256, 0, stream>>>(pm_bf, k_arr, v_arr);
  attn_kernel<<<256, 512, 0, stream>>>(q_arr, k_arr, v_arr, x_bf);
  gemm_bt_kernel<1><<<dim3(8, 64), 256, 0, stream>>>(x_bf, wout_bf, out, 8192, 1024, 1024);
}

// Round 2
// 274.873 us; speedup vs baseline: 1.0158x; 1.0158x over previous
//
#include <hip/hip_runtime.h>

typedef __bf16 bf16;
typedef __bf16 bf16x4 __attribute__((ext_vector_type(4)));
typedef __bf16 bf16x8 __attribute__((ext_vector_type(8)));
typedef float f32x4 __attribute__((ext_vector_type(4)));

#define LOG2E 1.44269504088896f

// async global->LDS, 16B per lane. LDS dest is wave-uniform base + lane*16
// (m104/m108): pass the lane-0 pointer; generic->AS(3) = low-32-bit truncation.
__device__ __forceinline__ void gl_lds16(const bf16* g, bf16* l) {
  __builtin_amdgcn_global_load_lds(
      reinterpret_cast<const __attribute__((address_space(1))) void*>((uintptr_t)g),
      reinterpret_cast<__attribute__((address_space(3))) void*>((uint32_t)(uintptr_t)l),
      16, 0, 0);
}

// ---------------- cast fp32 -> bf16 for weights + persistent mem ----------------
__global__ void cast3_kernel(const float* __restrict__ a, int na4, bf16* __restrict__ oa,
                             const float* __restrict__ b, int nb4, bf16* __restrict__ ob,
                             const float* __restrict__ c, int nc4, bf16* __restrict__ oc) {
  int i = blockIdx.x * blockDim.x + threadIdx.x;
  const float* src; bf16* dst; int idx;
  if (i < na4)            { src = a; dst = oa; idx = i; }
  else if (i < na4 + nb4) { src = b; dst = ob; idx = i - na4; }
  else if (i < na4 + nb4 + nc4) { src = c; dst = oc; idx = i - na4 - nb4; }
  else return;
  float4 v = ((const float4*)src)[idx];
  bf16x4 o = { (bf16)v.x, (bf16)v.y, (bf16)v.z, (bf16)v.w };
  ((bf16x4*)dst)[idx] = o;
}

// ---------------- RMSNorm: seq fp32 [8192][1024] -> x bf16 ----------------
__global__ __launch_bounds__(256) void rmsnorm_kernel(const float* __restrict__ seq,
                                                      const float* __restrict__ g,
                                                      bf16* __restrict__ xbf) {
  int row = blockIdx.x;
  int t = threadIdx.x;
  float4 x = ((const float4*)(seq + (size_t)row * 1024))[t];
  float ss = x.x*x.x + x.y*x.y + x.z*x.z + x.w*x.w;
  #pragma unroll
  for (int m = 32; m >= 1; m >>= 1) ss += __shfl_xor(ss, m, 64);
  __shared__ float red[4];
  if ((t & 63) == 0) red[t >> 6] = ss;
  __syncthreads();
  float tot = red[0] + red[1] + red[2] + red[3];
  float scale = rsqrtf(tot * (1.0f / 1024.0f) + 1.1920929e-07f);
  float4 gv = ((const float4*)g)[t];
  bf16x4 o = { (bf16)(x.x*scale*gv.x), (bf16)(x.y*scale*gv.y),
               (bf16)(x.z*scale*gv.z), (bf16)(x.w*scale*gv.w) };
  ((bf16x4*)(xbf + (size_t)row * 1024))[t] = o;
}

// ---------------- GEMM C[M,N] = A[M,K] * B[N,K]^T  (bf16 in, bf16/fp32 out) ----------------
// m97 structure: 128x128 tile, BK=32, 256 threads, global_load_lds width=16,
// unpadded LDS (stride 32 elems) -- padding breaks the lane-order contiguity
// requirement of global_load_lds.
template<int OUTF>
__global__ __launch_bounds__(256) void gemm_bt_kernel(const bf16* __restrict__ A,
                                                      const bf16* __restrict__ B,
                                                      void* __restrict__ C,
                                                      int M, int N, int K) {
  __shared__ bf16 As[128 * 32];
  __shared__ bf16 Bs[128 * 32];
  int t = threadIdx.x;
  int lane = t & 63, wv = t >> 6;
  int m16 = lane & 15, quad = lane >> 4;
  int bn = blockIdx.x, bm = blockIdx.y;
  const bf16* Ab = A + (size_t)bm * 128 * K;
  const bf16* Bb = B + (size_t)bn * 128 * K;
  int wr = (wv >> 1) * 64, wc = (wv & 1) * 64;
  f32x4 acc[4][4] = {};
  for (int k0 = 0; k0 < K; k0 += 32) {
    #pragma unroll
    for (int i = 0; i < 2; i++) {
      int cb = i * 256 + wv * 64;          // wave-uniform chunk base (16B chunks)
      int chunk = cb + lane;               // this lane's chunk
      int row = chunk >> 2, c = (chunk & 3) * 8;
      gl_lds16(Ab + (size_t)row * K + k0 + c, &As[cb * 8]);
      gl_lds16(Bb + (size_t)row * K + k0 + c, &Bs[cb * 8]);
    }
    __syncthreads();   // implicit s_waitcnt vmcnt(0) drains the LDS-DMA
    bf16x8 af[4], bfr[4];
    #pragma unroll
    for (int i = 0; i < 4; i++) af[i]  = *(const bf16x8*)(&As[(wr + i * 16 + m16) * 32 + quad * 8]);
    #pragma unroll
    for (int j = 0; j < 4; j++) bfr[j] = *(const bf16x8*)(&Bs[(wc + j * 16 + m16) * 32 + quad * 8]);
    #pragma unroll
    for (int i = 0; i < 4; i++)
      #pragma unroll
      for (int j = 0; j < 4; j++)
        acc[i][j] = __builtin_amdgcn_mfma_f32_16x16x32_bf16(af[i], bfr[j], acc[i][j], 0, 0, 0);
    __syncthreads();
  }
  #pragma unroll
  for (int i = 0; i < 4; i++)
    #pragma unroll
    for (int j = 0; j < 4; j++)
      #pragma unroll
      for (int r = 0; r < 4; r++) {
        size_t row = (size_t)bm * 128 + wr + i * 16 + quad * 4 + r;
        size_t col = (size_t)bn * 128 + wc + j * 16 + m16;
        float v = acc[i][j][r];
        if (OUTF) ((float*)C)[row * N + col] = v;
        else      ((bf16*)C)[row * N + col] = (bf16)v;
      }
}

// ---------------- RoPE + segment rearrange ----------------
// qkv bf16 [8192][3072] -> q [16][16][512][64] (pre-scaled by 1/8), k/v [16][16][528][64] rows 16..527
__global__ __launch_bounds__(128) void rope_seg_kernel(const bf16* __restrict__ qkv,
                                                       bf16* __restrict__ qa,
                                                       bf16* __restrict__ ka,
                                                       bf16* __restrict__ va) {
  int row = blockIdx.x, t = threadIdx.x;       // 8192 rows, 128 threads
  int h = t >> 3, d0 = (t & 7) * 8;
  int gb = row >> 12, pos = row & 4095, seg = (row >> 9) & 7, s = row & 511;
  const bf16* base = qkv + (size_t)row * 3072 + h * 64 + d0;
  bf16 qv[8], kv[8], vv[8];
  *(uint4*)qv = *(const uint4*)(base);
  *(uint4*)kv = *(const uint4*)(base + 1024);
  *(uint4*)vv = *(const uint4*)(base + 2048);
  bf16 qo[8], ko[8];
  #pragma unroll
  for (int p = 0; p < 4; p++) {
    int fi = (d0 >> 1) + p;                    // freq index 0..31
    float inv = exp2f((float)fi * -0.41524101186f);   // 10000^(-fi/32)
    float th = (float)pos * inv;
    float sn, cs;
    sincosf(th, &sn, &cs);
    float q0 = (float)qv[2 * p], q1 = (float)qv[2 * p + 1];
    float k0 = (float)kv[2 * p], k1 = (float)kv[2 * p + 1];
    qo[2 * p]     = (bf16)((q0 * cs - q1 * sn) * 0.125f);
    qo[2 * p + 1] = (bf16)((q1 * cs + q0 * sn) * 0.125f);
    ko[2 * p]     = (bf16)(k0 * cs - k1 * sn);
    ko[2 * p + 1] = (bf16)(k1 * cs + k0 * sn);
  }
  size_t bwh = ((size_t)(gb * 8 + seg) * 16 + h);
  size_t qoff = (bwh * 512 + s) * 64 + d0;
  *(uint4*)(qa + qoff) = *(uint4*)qo;
  size_t koff = (bwh * 528 + 16 + s) * 64 + d0;
  *(uint4*)(ka + koff) = *(uint4*)ko;
  *(uint4*)(va + koff) = *(uint4*)vv;
}

// ---------------- persistent-mem fill: k/v rows 0..15 ----------------
__global__ void pm_fill_kernel(const bf16* __restrict__ pmbf,
                               bf16* __restrict__ ka, bf16* __restrict__ va) {
  int idx = blockIdx.x * blockDim.x + threadIdx.x;   // 2*16*16*16*64 = 524288
  int d = idx & 63, r = (idx >> 6) & 15, h = (idx >> 10) & 15, bw = (idx >> 14) & 15, which = idx >> 18;
  bf16 val = pmbf[(((size_t)which * 16 + h) * 16 + r) * 64 + d];
  size_t off = (((size_t)bw * 16 + h) * 528 + r) * 64 + d;
  bf16* dst = which ? va : ka;
  dst[off] = val;
}

// ---------------- attention: one block per (bw,h), 8 waves ----------------
__global__ __launch_bounds__(512) void attn_kernel(const bf16* __restrict__ qa,
                                                   const bf16* __restrict__ ka,
                                                   const bf16* __restrict__ va,
                                                   bf16* __restrict__ ob) {
  __shared__ bf16 Ks[528 * 72];          // K rows, padded stride 72 (2-way bank alias = free)
  __shared__ bf16 Vt[64 * 536 + 16];     // V transposed [d][j], stride 536, zero-padded tail
  __shared__ bf16 Pb[8 * 16 * 40];       // per-wave P staging, stride 40
  int bh = blockIdx.x;
  int bw = bh >> 4, h = bh & 15;
  int t = threadIdx.x;
  int wv = t >> 6, lane = t & 63;
  int m16 = lane & 15, quad = lane >> 4;
  const bf16* kbase = ka + (size_t)bh * 528 * 64;
  const bf16* vbase = va + (size_t)bh * 528 * 64;
  const bf16* qbase = qa + (size_t)bh * 512 * 64;
  // stage K rows
  for (int ch = t; ch < 4224; ch += 512) {
    int row = ch >> 3, c8 = (ch & 7) * 8;
    *(uint4*)(&Ks[row * 72 + c8]) = *(const uint4*)(kbase + row * 64 + c8);
  }
  // stage V transposed
  for (int ch = t; ch < 4224; ch += 512) {
    int row = ch >> 3, d0 = (ch & 7) * 8;
    uint4 dta = *(const uint4*)(vbase + row * 64 + d0);
    bf16 tmp[8]; *(uint4*)tmp = dta;
    #pragma unroll
    for (int i = 0; i < 8; i++) Vt[(d0 + i) * 536 + row] = tmp[i];
  }
  // zero-pad Vt cols 528..535 and the tail so the ragged last chunk reads finite zeros
  if (t < 512) { int r = t >> 3, cc = 528 + (t & 7); Vt[r * 536 + cc] = (bf16)0.f; }
  if (t < 16) Vt[64 * 536 + t] = (bf16)0.f;
  __syncthreads();

  bf16* myP = &Pb[wv * 16 * 40];
  for (int pass = 0; pass < 4; pass++) {
    int q0 = pass * 128 + wv * 16;
    bf16x8 qf0 = *(const bf16x8*)(qbase + (size_t)(q0 + m16) * 64 + quad * 8);
    bf16x8 qf1 = *(const bf16x8*)(qbase + (size_t)(q0 + m16) * 64 + 32 + quad * 8);
    f32x4 s[33];
    #pragma unroll
    for (int tl = 0; tl < 33; tl++) {
      f32x4 acc = {0.f, 0.f, 0.f, 0.f};
      bf16x8 b0 = *(const bf16x8*)(&Ks[(tl * 16 + m16) * 72 + quad * 8]);
      bf16x8 b1 = *(const bf16x8*)(&Ks[(tl * 16 + m16) * 72 + 32 + quad * 8]);
      acc = __builtin_amdgcn_mfma_f32_16x16x32_bf16(qf0, b0, acc, 0, 0, 0);
      acc = __builtin_amdgcn_mfma_f32_16x16x32_bf16(qf1, b1, acc, 0, 0, 0);
      s[tl] = acc;
    }
    // causal mask: query i sees kv j iff j-16 <= i
    #pragma unroll
    for (int tl = 0; tl < 33; tl++) {
      int j = tl * 16 + m16;
      #pragma unroll
      for (int r = 0; r < 4; r++) {
        int i = q0 + quad * 4 + r;
        if (j - 16 > i) s[tl][r] = -1e30f;
      }
    }
    // softmax (full row available): reduce over 33 tiles + 16 lanes of the column group
    float lrow[4];
    #pragma unroll
    for (int r = 0; r < 4; r++) {
      float mx = s[0][r];
      #pragma unroll
      for (int tl = 1; tl < 33; tl++) mx = fmaxf(mx, s[tl][r]);
      mx = fmaxf(mx, __shfl_xor(mx, 1, 64));
      mx = fmaxf(mx, __shfl_xor(mx, 2, 64));
      mx = fmaxf(mx, __shfl_xor(mx, 4, 64));
      mx = fmaxf(mx, __shfl_xor(mx, 8, 64));
      float sum = 0.f;
      #pragma unroll
      for (int tl = 0; tl < 33; tl++) {
        float p = exp2f((s[tl][r] - mx) * LOG2E);
        s[tl][r] = p;
        sum += p;
      }
      sum += __shfl_xor(sum, 1, 64);
      sum += __shfl_xor(sum, 2, 64);
      sum += __shfl_xor(sum, 4, 64);
      sum += __shfl_xor(sum, 8, 64);
      lrow[r] = sum;
    }
    // PV: 17 chunks of 32 kv (last half-chunk zero-padded)
    f32x4 o[4] = {};
    for (int c = 0; c < 17; c++) {
      #pragma unroll
      for (int half = 0; half < 2; half++) {
        int tl = 2 * c + half;
        #pragma unroll
        for (int r = 0; r < 4; r++) {
          float pv = (tl < 33) ? s[tl][r] : 0.f;
          myP[(quad * 4 + r) * 40 + half * 16 + m16] = (bf16)pv;
        }
      }
      asm volatile("s_waitcnt lgkmcnt(0)" ::: "memory");   // wave-local: writes visible
      bf16x8 pf = *(const bf16x8*)(&myP[m16 * 40 + quad * 8]);
      #pragma unroll
      for (int dt = 0; dt < 4; dt++) {
        bf16x8 vf = *(const bf16x8*)(&Vt[(dt * 16 + m16) * 536 + c * 32 + quad * 8]);
        o[dt] = __builtin_amdgcn_mfma_f32_16x16x32_bf16(pf, vf, o[dt], 0, 0, 0);
      }
      asm volatile("s_waitcnt lgkmcnt(0)" ::: "memory");   // reads done before next overwrite
    }
    // normalize + write to [8192][1024] merged layout
    int gb = bw >> 3, seg = bw & 7;
    float invl[4];
    #pragma unroll
    for (int r = 0; r < 4; r++) invl[r] = 1.0f / lrow[r];
    #pragma unroll
    for (int dt = 0; dt < 4; dt++)
      #pragma unroll
      for (int r = 0; r < 4; r++) {
        size_t row = (size_t)gb * 4096 + seg * 512 + q0 + quad * 4 + r;
        ob[row * 1024 + h * 64 + dt * 16 + m16] = (bf16)(o[dt][r] * invl[r]);
      }
  }
}

// ---------------- launch ----------------
extern "C" void kernel_launch(void* const* d_in, const int* in_sizes, int n_in,
                              void* d_out, int out_size, void* d_ws, size_t ws_size,
                              hipStream_t stream) {
  const float* seq  = (const float*)d_in[0];
  const float* g    = (const float*)d_in[1];
  const float* wqkv = (const float*)d_in[2];
  const float* wout = (const float*)d_in[3];
  const float* pm   = (const float*)d_in[4];
  float* out = (float*)d_out;
  char* ws = (char*)d_ws;
  bf16* wqkv_bf = (bf16*)(ws);                    //  6,291,456
  bf16* wout_bf = (bf16*)(ws + 6291456);          //  2,097,152
  bf16* pm_bf   = (bf16*)(ws + 8388608);          //     65,536 (32768 elems)
  bf16* x_bf    = (bf16*)(ws + 8454144);          // 16,777,216 (reused as attn out)
  bf16* qkv_bf  = (bf16*)(ws + 25231360);         // 50,331,648
  bf16* q_arr   = (bf16*)(ws + 75563008);         // 16,777,216
  bf16* k_arr   = (bf16*)(ws + 92340224);         // 17,301,504
  bf16* v_arr   = (bf16*)(ws + 109641728);        // 17,301,504 -> 126,943,232 total

  cast3_kernel<<<4128, 256, 0, stream>>>(wqkv, 786432, wqkv_bf,
                                         wout, 262144, wout_bf,
                                         pm, 8192, pm_bf);
  rmsnorm_kernel<<<8192, 256, 0, stream>>>(seq, g, x_bf);
  gemm_bt_kernel<0><<<dim3(24, 64), 256, 0, stream>>>(x_bf, wqkv_bf, qkv_bf, 8192, 3072, 1024);
  rope_seg_kernel<<<8192, 128, 0, stream>>>(qkv_bf, q_arr, k_arr, v_arr);
  pm_fill_kernel<<<2048, 256, 0, stream>>>(pm_bf, k_arr, v_arr);
  attn_kernel<<<256, 512, 0, stream>>>(q_arr, k_arr, v_arr, x_bf);
  gemm_bt_kernel<1><<<dim3(8, 64), 256, 0, stream>>>(x_bf, wout_bf, out, 8192, 1024, 1024);
}

// Round 3
// 248.289 us; speedup vs baseline: 1.1246x; 1.1071x over previous
//
#include <hip/hip_runtime.h>

typedef __bf16 bf16;
typedef __bf16 bf16x4 __attribute__((ext_vector_type(4)));
typedef __bf16 bf16x8 __attribute__((ext_vector_type(8)));
typedef float f32x4 __attribute__((ext_vector_type(4)));

#define LOG2E 1.44269504088896f

// async global->LDS, 16B per lane. LDS dest is wave-uniform base + lane*16
// (m104/m108): pass the lane-0 pointer; generic->AS(3) = low-32-bit truncation.
__device__ __forceinline__ void gl_lds16(const bf16* g, bf16* l) {
  __builtin_amdgcn_global_load_lds(
      reinterpret_cast<const __attribute__((address_space(1))) void*>((uintptr_t)g),
      reinterpret_cast<__attribute__((address_space(3))) void*>((uint32_t)(uintptr_t)l),
      16, 0, 0);
}

// ---------------- cast fp32 -> bf16 for weights + pm, and build RoPE cos/sin table ----------------
__global__ void cast3_kernel(const float* __restrict__ a, int na4, bf16* __restrict__ oa,
                             const float* __restrict__ b, int nb4, bf16* __restrict__ ob,
                             const float* __restrict__ c, int nc4, bf16* __restrict__ oc,
                             float2* __restrict__ tab, int nt) {
  int i = blockIdx.x * blockDim.x + threadIdx.x;
  if (i < na4 + nb4 + nc4) {
    const float* src; bf16* dst; int idx;
    if (i < na4)            { src = a; dst = oa; idx = i; }
    else if (i < na4 + nb4) { src = b; dst = ob; idx = i - na4; }
    else                    { src = c; dst = oc; idx = i - na4 - nb4; }
    float4 v = ((const float4*)src)[idx];
    bf16x4 o = { (bf16)v.x, (bf16)v.y, (bf16)v.z, (bf16)v.w };
    ((bf16x4*)dst)[idx] = o;
  } else {
    int idx = i - (na4 + nb4 + nc4);
    if (idx >= nt) return;
    int pos = idx >> 5, fi = idx & 31;
    float inv = exp2f((float)fi * -0.41524101186f);   // 10000^(-fi/32)
    float th = (float)pos * inv;
    float sn, cs;
    sincosf(th, &sn, &cs);
    tab[idx] = make_float2(cs, sn);
  }
}

// ---------------- RMSNorm: seq fp32 [8192][1024] -> x bf16 ----------------
__global__ __launch_bounds__(256) void rmsnorm_kernel(const float* __restrict__ seq,
                                                      const float* __restrict__ g,
                                                      bf16* __restrict__ xbf) {
  int row = blockIdx.x;
  int t = threadIdx.x;
  float4 x = ((const float4*)(seq + (size_t)row * 1024))[t];
  float ss = x.x*x.x + x.y*x.y + x.z*x.z + x.w*x.w;
  #pragma unroll
  for (int m = 32; m >= 1; m >>= 1) ss += __shfl_xor(ss, m, 64);
  __shared__ float red[4];
  if ((t & 63) == 0) red[t >> 6] = ss;
  __syncthreads();
  float tot = red[0] + red[1] + red[2] + red[3];
  float scale = rsqrtf(tot * (1.0f / 1024.0f) + 1.1920929e-07f);
  float4 gv = ((const float4*)g)[t];
  bf16x4 o = { (bf16)(x.x*scale*gv.x), (bf16)(x.y*scale*gv.y),
               (bf16)(x.z*scale*gv.z), (bf16)(x.w*scale*gv.w) };
  ((bf16x4*)(xbf + (size_t)row * 1024))[t] = o;
}

// ---------------- GEMM C[M,N] = A[M,K] * B[N,K]^T  (bf16 in, bf16/fp32 out) ----------------
// BK=64: one staged tile per 64-K -> half the barrier drains of BK=32.
// LDS slot (row, p) holds global k-chunk g = p ^ (row&7): XOR swizzle keeps
// global_load_lds lane-contiguous on the LDS side while making the b128 frag
// reads exactly 2-way bank-aliased (free per m136).
template<int OUTF>
__global__ __launch_bounds__(256) void gemm_bt_kernel(const bf16* __restrict__ A,
                                                      const bf16* __restrict__ B,
                                                      void* __restrict__ C,
                                                      int M, int N, int K) {
  __shared__ bf16 As[128 * 64];
  __shared__ bf16 Bs[128 * 64];
  int t = threadIdx.x;
  int lane = t & 63, wv = t >> 6;
  int m16 = lane & 15, quad = lane >> 4;
  int bn = blockIdx.x, bm = blockIdx.y;
  const bf16* Ab = A + (size_t)bm * 128 * K;
  const bf16* Bb = B + (size_t)bn * 128 * K;
  int wr = (wv >> 1) * 64, wc = (wv & 1) * 64;
  f32x4 acc[4][4] = {};
  for (int k0 = 0; k0 < K; k0 += 64) {
    #pragma unroll
    for (int i = 0; i < 4; i++) {
      int cb = i * 256 + wv * 64;          // wave-uniform chunk base (16B chunks)
      int s = cb + lane;
      int row = s >> 3, p = s & 7, g = p ^ (row & 7);
      gl_lds16(Ab + (size_t)row * K + k0 + g * 8, &As[cb * 8]);
      gl_lds16(Bb + (size_t)row * K + k0 + g * 8, &Bs[cb * 8]);
    }
    __syncthreads();   // implicit s_waitcnt vmcnt(0) drains the LDS-DMA
    #pragma unroll
    for (int kk = 0; kk < 2; kk++) {
      bf16x8 af[4], bfr[4];
      #pragma unroll
      for (int i = 0; i < 4; i++) {
        int row = wr + i * 16 + m16;
        int p = (kk * 4 + quad) ^ (row & 7);
        af[i] = *(const bf16x8*)(&As[row * 64 + p * 8]);
      }
      #pragma unroll
      for (int j = 0; j < 4; j++) {
        int row = wc + j * 16 + m16;
        int p = (kk * 4 + quad) ^ (row & 7);
        bfr[j] = *(const bf16x8*)(&Bs[row * 64 + p * 8]);
      }
      #pragma unroll
      for (int i = 0; i < 4; i++)
        #pragma unroll
        for (int j = 0; j < 4; j++)
          acc[i][j] = __builtin_amdgcn_mfma_f32_16x16x32_bf16(af[i], bfr[j], acc[i][j], 0, 0, 0);
    }
    __syncthreads();
  }
  #pragma unroll
  for (int i = 0; i < 4; i++)
    #pragma unroll
    for (int j = 0; j < 4; j++)
      #pragma unroll
      for (int r = 0; r < 4; r++) {
        size_t row = (size_t)bm * 128 + wr + i * 16 + quad * 4 + r;
        size_t col = (size_t)bn * 128 + wc + j * 16 + m16;
        float v = acc[i][j][r];
        if (OUTF) ((float*)C)[row * N + col] = v;
        else      ((bf16*)C)[row * N + col] = (bf16)v;
      }
}

// ---------------- attention: one block per (bw,h), 8 waves; RoPE fused at staging ----------------
__global__ __launch_bounds__(512) void attn_kernel(const bf16* __restrict__ qkv,
                                                   const bf16* __restrict__ pmbf,
                                                   const float2* __restrict__ tab,
                                                   bf16* __restrict__ ob) {
  __shared__ bf16 Ks[528 * 72];          // K rows (rope'd), padded stride 72
  __shared__ bf16 Vt[64 * 536 + 16];     // V transposed [d][j], stride 536, zero-padded tail
  __shared__ bf16 Pb[8 * 16 * 40];       // per-wave P staging, stride 40
  int bh = blockIdx.x;
  int bw = bh >> 4, h = bh & 15;
  int seg = bw & 7;
  int t = threadIdx.x;
  int wv = t >> 6, lane = t & 63;
  int m16 = lane & 15, quad = lane >> 4;
  const bf16* qk_base = qkv + (size_t)bw * 512 * 3072 + h * 64;  // row s at +s*3072; K +1024; V +2048
  // stage K rows (pm rows 0..15 unroped, seq rows 16..527 roped at global pos)
  for (int ch = t; ch < 4224; ch += 512) {
    int row = ch >> 3, d0 = (ch & 7) * 8;
    bf16 tmp[8];
    if (row < 16) {
      *(uint4*)tmp = *(const uint4*)(pmbf + ((size_t)h * 16 + row) * 64 + d0);
    } else {
      int s = row - 16;
      *(uint4*)tmp = *(const uint4*)(qk_base + (size_t)s * 3072 + 1024 + d0);
      int pos = seg * 512 + s;
      const float2* tb = tab + pos * 32 + (d0 >> 1);
      #pragma unroll
      for (int p = 0; p < 4; p++) {
        float2 cs = tb[p];
        float x0 = (float)tmp[2 * p], x1 = (float)tmp[2 * p + 1];
        tmp[2 * p]     = (bf16)(x0 * cs.x - x1 * cs.y);
        tmp[2 * p + 1] = (bf16)(x1 * cs.x + x0 * cs.y);
      }
    }
    *(uint4*)(&Ks[row * 72 + d0]) = *(uint4*)tmp;
  }
  // stage V transposed (no rope)
  for (int ch = t; ch < 4224; ch += 512) {
    int row = ch >> 3, d0 = (ch & 7) * 8;
    bf16 tmp[8];
    if (row < 16) *(uint4*)tmp = *(const uint4*)(pmbf + ((size_t)(16 + h) * 16 + row) * 64 + d0);
    else          *(uint4*)tmp = *(const uint4*)(qk_base + (size_t)(row - 16) * 3072 + 2048 + d0);
    #pragma unroll
    for (int i = 0; i < 8; i++) Vt[(d0 + i) * 536 + row] = tmp[i];
  }
  // zero-pad Vt cols 528..535 and the tail so the ragged last chunk reads finite zeros
  if (t < 512) { int r = t >> 3, cc = 528 + (t & 7); Vt[r * 536 + cc] = (bf16)0.f; }
  if (t < 16) Vt[64 * 536 + t] = (bf16)0.f;
  __syncthreads();

  bf16* myP = &Pb[wv * 16 * 40];
  for (int pass = 0; pass < 4; pass++) {
    int q0 = pass * 128 + wv * 16;
    int qrow = q0 + m16;
    int pos = seg * 512 + qrow;
    const bf16* qp = qk_base + (size_t)qrow * 3072;
    // load Q frags + rope + 1/8 scale in registers
    bf16 qr0[8], qr1[8];
    *(uint4*)qr0 = *(const uint4*)(qp + quad * 8);
    *(uint4*)qr1 = *(const uint4*)(qp + 32 + quad * 8);
    {
      const float2* tb0 = tab + pos * 32 + quad * 4;
      const float2* tb1 = tb0 + 16;
      #pragma unroll
      for (int p = 0; p < 4; p++) {
        float2 c0 = tb0[p], c1 = tb1[p];
        float a0 = (float)qr0[2 * p], a1 = (float)qr0[2 * p + 1];
        qr0[2 * p]     = (bf16)((a0 * c0.x - a1 * c0.y) * 0.125f);
        qr0[2 * p + 1] = (bf16)((a1 * c0.x + a0 * c0.y) * 0.125f);
        float b0 = (float)qr1[2 * p], b1 = (float)qr1[2 * p + 1];
        qr1[2 * p]     = (bf16)((b0 * c1.x - b1 * c1.y) * 0.125f);
        qr1[2 * p + 1] = (bf16)((b1 * c1.x + b0 * c1.y) * 0.125f);
      }
    }
    bf16x8 qf0 = *(bf16x8*)qr0;
    bf16x8 qf1 = *(bf16x8*)qr1;
    f32x4 s[33];
    #pragma unroll
    for (int tl = 0; tl < 33; tl++) {
      f32x4 acc = {0.f, 0.f, 0.f, 0.f};
      bf16x8 b0 = *(const bf16x8*)(&Ks[(tl * 16 + m16) * 72 + quad * 8]);
      bf16x8 b1 = *(const bf16x8*)(&Ks[(tl * 16 + m16) * 72 + 32 + quad * 8]);
      acc = __builtin_amdgcn_mfma_f32_16x16x32_bf16(qf0, b0, acc, 0, 0, 0);
      acc = __builtin_amdgcn_mfma_f32_16x16x32_bf16(qf1, b1, acc, 0, 0, 0);
      s[tl] = acc;
    }
    // causal mask: query i sees kv j iff j-16 <= i
    #pragma unroll
    for (int tl = 0; tl < 33; tl++) {
      int j = tl * 16 + m16;
      #pragma unroll
      for (int r = 0; r < 4; r++) {
        int i = q0 + quad * 4 + r;
        if (j - 16 > i) s[tl][r] = -1e30f;
      }
    }
    // softmax (full row): reduce over 33 tiles + 16 lanes of the column group
    float lrow[4];
    #pragma unroll
    for (int r = 0; r < 4; r++) {
      float mx = s[0][r];
      #pragma unroll
      for (int tl = 1; tl < 33; tl++) mx = fmaxf(mx, s[tl][r]);
      mx = fmaxf(mx, __shfl_xor(mx, 1, 64));
      mx = fmaxf(mx, __shfl_xor(mx, 2, 64));
      mx = fmaxf(mx, __shfl_xor(mx, 4, 64));
      mx = fmaxf(mx, __shfl_xor(mx, 8, 64));
      float sum = 0.f;
      #pragma unroll
      for (int tl = 0; tl < 33; tl++) {
        float p = exp2f((s[tl][r] - mx) * LOG2E);
        s[tl][r] = p;
        sum += p;
      }
      sum += __shfl_xor(sum, 1, 64);
      sum += __shfl_xor(sum, 2, 64);
      sum += __shfl_xor(sum, 4, 64);
      sum += __shfl_xor(sum, 8, 64);
      lrow[r] = sum;
    }
    // PV: 17 chunks of 32 kv (last half-chunk zero-padded)
    f32x4 o[4] = {};
    for (int c = 0; c < 17; c++) {
      #pragma unroll
      for (int half = 0; half < 2; half++) {
        int tl = 2 * c + half;
        #pragma unroll
        for (int r = 0; r < 4; r++) {
          float pv = (tl < 33) ? s[tl][r] : 0.f;
          myP[(quad * 4 + r) * 40 + half * 16 + m16] = (bf16)pv;
        }
      }
      asm volatile("s_waitcnt lgkmcnt(0)" ::: "memory");   // wave-local: writes visible
      bf16x8 pf = *(const bf16x8*)(&myP[m16 * 40 + quad * 8]);
      #pragma unroll
      for (int dt = 0; dt < 4; dt++) {
        bf16x8 vf = *(const bf16x8*)(&Vt[(dt * 16 + m16) * 536 + c * 32 + quad * 8]);
        o[dt] = __builtin_amdgcn_mfma_f32_16x16x32_bf16(pf, vf, o[dt], 0, 0, 0);
      }
      asm volatile("s_waitcnt lgkmcnt(0)" ::: "memory");   // reads done before next overwrite
    }
    // normalize + write to [8192][1024] merged layout
    float invl[4];
    #pragma unroll
    for (int r = 0; r < 4; r++) invl[r] = 1.0f / lrow[r];
    #pragma unroll
    for (int dt = 0; dt < 4; dt++)
      #pragma unroll
      for (int r = 0; r < 4; r++) {
        size_t row = (size_t)bw * 512 + q0 + quad * 4 + r;
        ob[row * 1024 + h * 64 + dt * 16 + m16] = (bf16)(o[dt][r] * invl[r]);
      }
  }
}

// ---------------- launch ----------------
extern "C" void kernel_launch(void* const* d_in, const int* in_sizes, int n_in,
                              void* d_out, int out_size, void* d_ws, size_t ws_size,
                              hipStream_t stream) {
  const float* seq  = (const float*)d_in[0];
  const float* g    = (const float*)d_in[1];
  const float* wqkv = (const float*)d_in[2];
  const float* wout = (const float*)d_in[3];
  const float* pm   = (const float*)d_in[4];
  float* out = (float*)d_out;
  char* ws = (char*)d_ws;
  bf16*   wqkv_bf = (bf16*)(ws);                  //  6,291,456
  bf16*   wout_bf = (bf16*)(ws + 6291456);        //  2,097,152
  bf16*   pm_bf   = (bf16*)(ws + 8388608);        //     65,536
  float2* tab     = (float2*)(ws + 8454144);      //  1,048,576 (4096 x 32 cos/sin)
  bf16*   x_bf    = (bf16*)(ws + 9502720);        // 16,777,216 (RMSNorm out, reused as attn out)
  bf16*   qkv_bf  = (bf16*)(ws + 26279936);       // 50,331,648 -> 76,611,584 total

  cast3_kernel<<<4640, 256, 0, stream>>>(wqkv, 786432, wqkv_bf,
                                         wout, 262144, wout_bf,
                                         pm, 8192, pm_bf,
                                         tab, 131072);
  rmsnorm_kernel<<<8192, 256, 0, stream>>>(seq, g, x_bf);
  gemm_bt_kernel<0><<<dim3(24, 64), 256, 0, stream>>>(x_bf, wqkv_bf, qkv_bf, 8192, 3072, 1024);
  attn_kernel<<<256, 512, 0, stream>>>(qkv_bf, pm_bf, tab, x_bf);
  gemm_bt_kernel<1><<<dim3(8, 64), 256, 0, stream>>>(x_bf, wout_bf, out, 8192, 1024, 1024);
}

// Round 4
// 232.003 us; speedup vs baseline: 1.2035x; 1.0702x over previous
//
#include <hip/hip_runtime.h>

typedef __bf16 bf16;
typedef __bf16 bf16x4 __attribute__((ext_vector_type(4)));
typedef __bf16 bf16x8 __attribute__((ext_vector_type(8)));
typedef float f32x4 __attribute__((ext_vector_type(4)));

#define LOG2E 1.44269504088896f

// async global->LDS, 16B per lane. LDS dest is wave-uniform base + lane*16
// (m104/m108): pass the lane-0 pointer; generic->AS(3) = low-32-bit truncation.
__device__ __forceinline__ void gl_lds16(const bf16* g, bf16* l) {
  __builtin_amdgcn_global_load_lds(
      reinterpret_cast<const __attribute__((address_space(1))) void*>((uintptr_t)g),
      reinterpret_cast<__attribute__((address_space(3))) void*>((uint32_t)(uintptr_t)l),
      16, 0, 0);
}

// ---------------- cast fp32 -> bf16 for weights + pm, and build RoPE cos/sin table ----------------
__global__ void cast3_kernel(const float* __restrict__ a, int na4, bf16* __restrict__ oa,
                             const float* __restrict__ b, int nb4, bf16* __restrict__ ob,
                             const float* __restrict__ c, int nc4, bf16* __restrict__ oc,
                             float2* __restrict__ tab, int nt) {
  int i = blockIdx.x * blockDim.x + threadIdx.x;
  if (i < na4 + nb4 + nc4) {
    const float* src; bf16* dst; int idx;
    if (i < na4)            { src = a; dst = oa; idx = i; }
    else if (i < na4 + nb4) { src = b; dst = ob; idx = i - na4; }
    else                    { src = c; dst = oc; idx = i - na4 - nb4; }
    float4 v = ((const float4*)src)[idx];
    bf16x4 o = { (bf16)v.x, (bf16)v.y, (bf16)v.z, (bf16)v.w };
    ((bf16x4*)dst)[idx] = o;
  } else {
    int idx = i - (na4 + nb4 + nc4);
    if (idx >= nt) return;
    int pos = idx >> 5, fi = idx & 31;
    float inv = exp2f((float)fi * -0.41524101186f);   // 10000^(-fi/32)
    float th = (float)pos * inv;
    float sn, cs;
    sincosf(th, &sn, &cs);
    tab[idx] = make_float2(cs, sn);
  }
}

// ---------------- RMSNorm: seq fp32 [8192][1024] -> x bf16 ----------------
__global__ __launch_bounds__(256) void rmsnorm_kernel(const float* __restrict__ seq,
                                                      const float* __restrict__ g,
                                                      bf16* __restrict__ xbf) {
  int row = blockIdx.x;
  int t = threadIdx.x;
  float4 x = ((const float4*)(seq + (size_t)row * 1024))[t];
  float ss = x.x*x.x + x.y*x.y + x.z*x.z + x.w*x.w;
  #pragma unroll
  for (int m = 32; m >= 1; m >>= 1) ss += __shfl_xor(ss, m, 64);
  __shared__ float red[4];
  if ((t & 63) == 0) red[t >> 6] = ss;
  __syncthreads();
  float tot = red[0] + red[1] + red[2] + red[3];
  float scale = rsqrtf(tot * (1.0f / 1024.0f) + 1.1920929e-07f);
  float4 gv = ((const float4*)g)[t];
  bf16x4 o = { (bf16)(x.x*scale*gv.x), (bf16)(x.y*scale*gv.y),
               (bf16)(x.z*scale*gv.z), (bf16)(x.w*scale*gv.w) };
  ((bf16x4*)(xbf + (size_t)row * 1024))[t] = o;
}

// ---------------- GEMM C[M,N] = A[M,K] * B[N,K]^T  (bf16 in, bf16/fp32 out) ----------------
// BK=64, XOR-swizzled LDS, global_load_lds width=16 (m97 lineage).
template<int OUTF>
__global__ __launch_bounds__(256) void gemm_bt_kernel(const bf16* __restrict__ A,
                                                      const bf16* __restrict__ B,
                                                      void* __restrict__ C,
                                                      int M, int N, int K) {
  __shared__ bf16 As[128 * 64];
  __shared__ bf16 Bs[128 * 64];
  int t = threadIdx.x;
  int lane = t & 63, wv = t >> 6;
  int m16 = lane & 15, quad = lane >> 4;
  int bn = blockIdx.x, bm = blockIdx.y;
  const bf16* Ab = A + (size_t)bm * 128 * K;
  const bf16* Bb = B + (size_t)bn * 128 * K;
  int wr = (wv >> 1) * 64, wc = (wv & 1) * 64;
  f32x4 acc[4][4] = {};
  for (int k0 = 0; k0 < K; k0 += 64) {
    #pragma unroll
    for (int i = 0; i < 4; i++) {
      int cb = i * 256 + wv * 64;          // wave-uniform chunk base (16B chunks)
      int s = cb + lane;
      int row = s >> 3, p = s & 7, g = p ^ (row & 7);
      gl_lds16(Ab + (size_t)row * K + k0 + g * 8, &As[cb * 8]);
      gl_lds16(Bb + (size_t)row * K + k0 + g * 8, &Bs[cb * 8]);
    }
    __syncthreads();   // implicit s_waitcnt vmcnt(0) drains the LDS-DMA
    #pragma unroll
    for (int kk = 0; kk < 2; kk++) {
      bf16x8 af[4], bfr[4];
      #pragma unroll
      for (int i = 0; i < 4; i++) {
        int row = wr + i * 16 + m16;
        int p = (kk * 4 + quad) ^ (row & 7);
        af[i] = *(const bf16x8*)(&As[row * 64 + p * 8]);
      }
      #pragma unroll
      for (int j = 0; j < 4; j++) {
        int row = wc + j * 16 + m16;
        int p = (kk * 4 + quad) ^ (row & 7);
        bfr[j] = *(const bf16x8*)(&Bs[row * 64 + p * 8]);
      }
      #pragma unroll
      for (int i = 0; i < 4; i++)
        #pragma unroll
        for (int j = 0; j < 4; j++)
          acc[i][j] = __builtin_amdgcn_mfma_f32_16x16x32_bf16(af[i], bfr[j], acc[i][j], 0, 0, 0);
    }
    __syncthreads();
  }
  #pragma unroll
  for (int i = 0; i < 4; i++)
    #pragma unroll
    for (int j = 0; j < 4; j++)
      #pragma unroll
      for (int r = 0; r < 4; r++) {
        size_t row = (size_t)bm * 128 + wr + i * 16 + quad * 4 + r;
        size_t col = (size_t)bn * 128 + wc + j * 16 + m16;
        float v = acc[i][j][r];
        if (OUTF) ((float*)C)[row * N + col] = v;
        else      ((bf16*)C)[row * N + col] = (bf16)v;
      }
}

// ---------------- attention: one block per (bw,h), 8 waves; RoPE fused; causal skip ----------------
// q-tile index qi: only score tiles 0..qi+1 are (partially) visible; only the
// diagonal tile tl==qi+1 needs masking, with the position-independent pattern
// m16 > quad*4+r. Wave balance: qi = {wv, 15-wv, 16+wv, 31-wv} -> 70 tile-units
// per wave for every wv. All guards are wave-uniform -> s_cbranch, and the
// score array s[33] keeps static indexing (no scratch spill).
__global__ __launch_bounds__(512) void attn_kernel(const bf16* __restrict__ qkv,
                                                   const bf16* __restrict__ pmbf,
                                                   const float2* __restrict__ tab,
                                                   bf16* __restrict__ ob) {
  __shared__ bf16 Ks[528 * 72];          // K rows (rope'd), padded stride 72
  __shared__ bf16 Vt[64 * 536 + 16];     // V transposed [d][j], stride 536, zero-padded tail
  __shared__ bf16 Pb[8 * 16 * 40];       // per-wave P staging, stride 40
  int bh = blockIdx.x;
  int bw = bh >> 4, h = bh & 15;
  int seg = bw & 7;
  int t = threadIdx.x;
  int wv = t >> 6, lane = t & 63;
  int m16 = lane & 15, quad = lane >> 4;
  const bf16* qk_base = qkv + (size_t)bw * 512 * 3072 + h * 64;  // row s at +s*3072; K +1024; V +2048
  // stage K rows (pm rows 0..15 unroped, seq rows 16..527 roped at global pos)
  for (int ch = t; ch < 4224; ch += 512) {
    int row = ch >> 3, d0 = (ch & 7) * 8;
    bf16 tmp[8];
    if (row < 16) {
      *(uint4*)tmp = *(const uint4*)(pmbf + ((size_t)h * 16 + row) * 64 + d0);
    } else {
      int s = row - 16;
      *(uint4*)tmp = *(const uint4*)(qk_base + (size_t)s * 3072 + 1024 + d0);
      int pos = seg * 512 + s;
      const float2* tb = tab + pos * 32 + (d0 >> 1);
      #pragma unroll
      for (int p = 0; p < 4; p++) {
        float2 cs = tb[p];
        float x0 = (float)tmp[2 * p], x1 = (float)tmp[2 * p + 1];
        tmp[2 * p]     = (bf16)(x0 * cs.x - x1 * cs.y);
        tmp[2 * p + 1] = (bf16)(x1 * cs.x + x0 * cs.y);
      }
    }
    *(uint4*)(&Ks[row * 72 + d0]) = *(uint4*)tmp;
  }
  // stage V transposed (no rope)
  for (int ch = t; ch < 4224; ch += 512) {
    int row = ch >> 3, d0 = (ch & 7) * 8;
    bf16 tmp[8];
    if (row < 16) *(uint4*)tmp = *(const uint4*)(pmbf + ((size_t)(16 + h) * 16 + row) * 64 + d0);
    else          *(uint4*)tmp = *(const uint4*)(qk_base + (size_t)(row - 16) * 3072 + 2048 + d0);
    #pragma unroll
    for (int i = 0; i < 8; i++) Vt[(d0 + i) * 536 + row] = tmp[i];
  }
  // zero-pad Vt cols 528..535 and the tail so ragged chunks read finite zeros
  if (t < 512) { int r = t >> 3, cc = 528 + (t & 7); Vt[r * 536 + cc] = (bf16)0.f; }
  if (t < 16) Vt[64 * 536 + t] = (bf16)0.f;
  __syncthreads();

  bf16* myP = &Pb[wv * 16 * 40];
  for (int pass = 0; pass < 4; pass++) {
    int qi = (pass == 0) ? wv : (pass == 1) ? 15 - wv : (pass == 2) ? 16 + wv : 31 - wv;
    int q0 = qi * 16;
    int ntl = qi + 2;                       // visible score tiles: 0..qi+1
    int qrow = q0 + m16;
    int pos = seg * 512 + qrow;
    const bf16* qp = qk_base + (size_t)qrow * 3072;
    // load Q frags + rope + 1/8 scale in registers
    bf16 qr0[8], qr1[8];
    *(uint4*)qr0 = *(const uint4*)(qp + quad * 8);
    *(uint4*)qr1 = *(const uint4*)(qp + 32 + quad * 8);
    {
      const float2* tb0 = tab + pos * 32 + quad * 4;
      const float2* tb1 = tb0 + 16;
      #pragma unroll
      for (int p = 0; p < 4; p++) {
        float2 c0 = tb0[p], c1 = tb1[p];
        float a0 = (float)qr0[2 * p], a1 = (float)qr0[2 * p + 1];
        qr0[2 * p]     = (bf16)((a0 * c0.x - a1 * c0.y) * 0.125f);
        qr0[2 * p + 1] = (bf16)((a1 * c0.x + a0 * c0.y) * 0.125f);
        float b0 = (float)qr1[2 * p], b1 = (float)qr1[2 * p + 1];
        qr1[2 * p]     = (bf16)((b0 * c1.x - b1 * c1.y) * 0.125f);
        qr1[2 * p + 1] = (bf16)((b1 * c1.x + b0 * c1.y) * 0.125f);
      }
    }
    bf16x8 qf0 = *(bf16x8*)qr0;
    bf16x8 qf1 = *(bf16x8*)qr1;
    f32x4 s[33];
    #pragma unroll
    for (int tl = 0; tl < 33; tl++) {
      if (tl < ntl) {                       // wave-uniform guard
        f32x4 acc = {0.f, 0.f, 0.f, 0.f};
        bf16x8 b0 = *(const bf16x8*)(&Ks[(tl * 16 + m16) * 72 + quad * 8]);
        bf16x8 b1 = *(const bf16x8*)(&Ks[(tl * 16 + m16) * 72 + 32 + quad * 8]);
        acc = __builtin_amdgcn_mfma_f32_16x16x32_bf16(qf0, b0, acc, 0, 0, 0);
        acc = __builtin_amdgcn_mfma_f32_16x16x32_bf16(qf1, b1, acc, 0, 0, 0);
        if (tl == qi + 1) {                 // diagonal tile: mask m16 > quad*4+r
          #pragma unroll
          for (int r = 0; r < 4; r++)
            if (m16 > quad * 4 + r) acc[r] = -1e30f;
        }
        s[tl] = acc;
      }
    }
    // softmax over visible tiles + 16 lanes of the column group
    float lrow[4];
    #pragma unroll
    for (int r = 0; r < 4; r++) {
      float mx = s[0][r];
      #pragma unroll
      for (int tl = 1; tl < 33; tl++) if (tl < ntl) mx = fmaxf(mx, s[tl][r]);
      mx = fmaxf(mx, __shfl_xor(mx, 1, 64));
      mx = fmaxf(mx, __shfl_xor(mx, 2, 64));
      mx = fmaxf(mx, __shfl_xor(mx, 4, 64));
      mx = fmaxf(mx, __shfl_xor(mx, 8, 64));
      float sum = 0.f;
      #pragma unroll
      for (int tl = 0; tl < 33; tl++) {
        if (tl < ntl) {
          float p = exp2f((s[tl][r] - mx) * LOG2E);
          s[tl][r] = p;
          sum += p;
        }
      }
      sum += __shfl_xor(sum, 1, 64);
      sum += __shfl_xor(sum, 2, 64);
      sum += __shfl_xor(sum, 4, 64);
      sum += __shfl_xor(sum, 8, 64);
      lrow[r] = sum;
    }
    // PV over visible chunks of 32 kv (ragged tail zero-filled)
    f32x4 o[4] = {};
    #pragma unroll
    for (int c = 0; c < 17; c++) {
      if (2 * c < ntl) {                    // wave-uniform guard
        #pragma unroll
        for (int half = 0; half < 2; half++) {
          int tl = 2 * c + half;
          #pragma unroll
          for (int r = 0; r < 4; r++) {
            float pv = (tl < ntl) ? s[tl][r] : 0.f;
            myP[(quad * 4 + r) * 40 + half * 16 + m16] = (bf16)pv;
          }
        }
        asm volatile("s_waitcnt lgkmcnt(0)" ::: "memory");   // wave-local: writes visible
        bf16x8 pf = *(const bf16x8*)(&myP[m16 * 40 + quad * 8]);
        #pragma unroll
        for (int dt = 0; dt < 4; dt++) {
          bf16x8 vf = *(const bf16x8*)(&Vt[(dt * 16 + m16) * 536 + c * 32 + quad * 8]);
          o[dt] = __builtin_amdgcn_mfma_f32_16x16x32_bf16(pf, vf, o[dt], 0, 0, 0);
        }
        asm volatile("s_waitcnt lgkmcnt(0)" ::: "memory");   // reads done before next overwrite
      }
    }
    // normalize + write to [8192][1024] merged layout
    float invl[4];
    #pragma unroll
    for (int r = 0; r < 4; r++) invl[r] = 1.0f / lrow[r];
    #pragma unroll
    for (int dt = 0; dt < 4; dt++)
      #pragma unroll
      for (int r = 0; r < 4; r++) {
        size_t row = (size_t)bw * 512 + q0 + quad * 4 + r;
        ob[row * 1024 + h * 64 + dt * 16 + m16] = (bf16)(o[dt][r] * invl[r]);
      }
  }
}

// ---------------- launch ----------------
extern "C" void kernel_launch(void* const* d_in, const int* in_sizes, int n_in,
                              void* d_out, int out_size, void* d_ws, size_t ws_size,
                              hipStream_t stream) {
  const float* seq  = (const float*)d_in[0];
  const float* g    = (const float*)d_in[1];
  const float* wqkv = (const float*)d_in[2];
  const float* wout = (const float*)d_in[3];
  const float* pm   = (const float*)d_in[4];
  float* out = (float*)d_out;
  char* ws = (char*)d_ws;
  bf16*   wqkv_bf = (bf16*)(ws);                  //  6,291,456
  bf16*   wout_bf = (bf16*)(ws + 6291456);        //  2,097,152
  bf16*   pm_bf   = (bf16*)(ws + 8388608);        //     65,536
  float2* tab     = (float2*)(ws + 8454144);      //  1,048,576 (4096 x 32 cos/sin)
  bf16*   x_bf    = (bf16*)(ws + 9502720);        // 16,777,216 (RMSNorm out, reused as attn out)
  bf16*   qkv_bf  = (bf16*)(ws + 26279936);       // 50,331,648 -> 76,611,584 total

  cast3_kernel<<<4640, 256, 0, stream>>>(wqkv, 786432, wqkv_bf,
                                         wout, 262144, wout_bf,
                                         pm, 8192, pm_bf,
                                         tab, 131072);
  rmsnorm_kernel<<<8192, 256, 0, stream>>>(seq, g, x_bf);
  gemm_bt_kernel<0><<<dim3(24, 64), 256, 0, stream>>>(x_bf, wqkv_bf, qkv_bf, 8192, 3072, 1024);
  attn_kernel<<<256, 512, 0, stream>>>(qkv_bf, pm_bf, tab, x_bf);
  gemm_bt_kernel<1><<<dim3(8, 64), 256, 0, stream>>>(x_bf, wout_bf, out, 8192, 1024, 1024);
}